// Round 2
// baseline (547.977 us; speedup 1.0000x reference)
//
#include <hip/hip_runtime.h>
#include <cstdint>
#include <cstddef>

typedef __attribute__((ext_vector_type(4))) float f32x4;
typedef __attribute__((ext_vector_type(8))) short s16x8;
typedef __attribute__((ext_vector_type(8))) __bf16 bf16x8;
typedef unsigned short u16;
typedef unsigned int u32;

// ---------- helpers ----------
__device__ __forceinline__ u16 f2bf(float f) {
    u32 u = __float_as_uint(f);
    u32 r = u + 0x7fffu + ((u >> 16) & 1u);   // RNE
    return (u16)(r >> 16);
}
__device__ __forceinline__ float bf2f(u16 u) {
    return __uint_as_float(((u32)u) << 16);
}
__device__ __forceinline__ f32x4 mfma_bf16(s16x8 a, s16x8 b, f32x4 c) {
    return __builtin_amdgcn_mfma_f32_16x16x32_bf16(
        __builtin_bit_cast(bf16x8, a), __builtin_bit_cast(bf16x8, b), c, 0, 0, 0);
}

// ---------- fp32 -> bf16 elementwise ----------
__global__ __launch_bounds__(256) void k_cvt(const float* __restrict__ in,
                                             u16* __restrict__ out, int n4) {
    int i = blockIdx.x * 256 + threadIdx.x;
    int stride = gridDim.x * 256;
    for (; i < n4; i += stride) {
        float4 v = reinterpret_cast<const float4*>(in)[i];
        u32 lo = (u32)f2bf(v.x) | ((u32)f2bf(v.y) << 16);
        u32 hi = (u32)f2bf(v.z) | ((u32)f2bf(v.w) << 16);
        reinterpret_cast<uint2*>(out)[i] = make_uint2(lo, hi);
    }
}

// ---------- transpose + convert: in (R,C) fp32 -> out (C,R) bf16 ----------
__global__ __launch_bounds__(256) void k_tcvt(const float* __restrict__ in,
                                              u16* __restrict__ out, int R, int C) {
    __shared__ float lt[32][33];
    int r0 = blockIdx.x << 5, c0 = blockIdx.y << 5;
    int tid = threadIdx.x, rr = tid >> 5, cc = tid & 31;
#pragma unroll
    for (int j = 0; j < 4; ++j)
        lt[rr + j * 8][cc] = in[(size_t)(r0 + rr + j * 8) * C + c0 + cc];
    __syncthreads();
#pragma unroll
    for (int j = 0; j < 4; ++j)
        out[(size_t)(c0 + rr + j * 8) * R + r0 + cc] = f2bf(lt[cc][rr + j * 8]);
}

// ---------- bf16 GEMM: A (M,K) row-major, Bt (N,K) row-major, C (M,N) ----------
// 128x128 tile, BK=64, 4 waves (each 64x64), XOR-swizzled LDS, reg-staged.
template <int OUT_BF16>
__global__ __launch_bounds__(256) void k_gemm(const u16* __restrict__ A,
                                              const u16* __restrict__ Bt,
                                              void* __restrict__ Cv,
                                              int M, int N, int K) {
    __shared__ u16 sA[128 * 64];
    __shared__ u16 sB[128 * 64];
    const int tid = threadIdx.x;
    const int w = tid >> 6, l = tid & 63;
    const int m0 = blockIdx.x << 7, n0 = blockIdx.y << 7;
    const int wr = (w >> 1) << 6, wc = (w & 1) << 6;
    const int lr = l & 15, lg = l >> 4;
    f32x4 acc[4][4] = {};
    const int nkt = K >> 6;
    for (int kt = 0; kt < nkt; ++kt) {
        const int k0 = kt << 6;
        __syncthreads();
#pragma unroll
        for (int j = 0; j < 4; ++j) {
            int chunk = tid + (j << 8);
            int row = chunk >> 3, c8 = chunk & 7;
            uint4 va = *reinterpret_cast<const uint4*>(&A[(size_t)(m0 + row) * K + k0 + (c8 << 3)]);
            uint4 vb = *reinterpret_cast<const uint4*>(&Bt[(size_t)(n0 + row) * K + k0 + (c8 << 3)]);
            int sc = (c8 ^ (row & 7)) << 3;
            *reinterpret_cast<uint4*>(&sA[(row << 6) + sc]) = va;
            *reinterpret_cast<uint4*>(&sB[(row << 6) + sc]) = vb;
        }
        __syncthreads();
#pragma unroll
        for (int ks = 0; ks < 2; ++ks) {
            s16x8 af[4], bfr[4];
#pragma unroll
            for (int i = 0; i < 4; ++i) {
                int ra = wr + (i << 4) + lr;
                int ca = (((ks << 2) + lg) ^ (ra & 7)) << 3;
                af[i] = *reinterpret_cast<const s16x8*>(&sA[(ra << 6) + ca]);
                int rb = wc + (i << 4) + lr;
                int cb = (((ks << 2) + lg) ^ (rb & 7)) << 3;
                bfr[i] = *reinterpret_cast<const s16x8*>(&sB[(rb << 6) + cb]);
            }
#pragma unroll
            for (int i = 0; i < 4; ++i)
#pragma unroll
                for (int jn = 0; jn < 4; ++jn)
                    acc[i][jn] = mfma_bf16(af[i], bfr[jn], acc[i][jn]);
        }
    }
#pragma unroll
    for (int i = 0; i < 4; ++i) {
        int rbase = m0 + wr + (i << 4) + (lg << 2);
#pragma unroll
        for (int jn = 0; jn < 4; ++jn) {
            int c = n0 + wc + (jn << 4) + lr;
#pragma unroll
            for (int r = 0; r < 4; ++r) {
                size_t idx = (size_t)(rbase + r) * N + c;
                if (OUT_BF16)
                    ((u16*)Cv)[idx] = f2bf(acc[i][jn][r]);
                else
                    ((float*)Cv)[idx] = acc[i][jn][r];
            }
        }
    }
}

// ---------- RoPE + head-major relayout ----------
// xin: (B*T, instride) bf16 rows (h-major cols, HD=128 per head)
// xout: (B, nH, T, 128) bf16, scaled by `scale` (Q folds softmax scale*log2e)
__global__ void k_rope(const u16* __restrict__ xin, int instride,
                       const int* __restrict__ pos, u16* __restrict__ xout,
                       int nH, float scale) {
    __shared__ float scs[64], sss[64];
    int bt = blockIdx.x;
    int b = bt >> 11, t = bt & 2047;
    int tid = threadIdx.x;
    if (tid < 64) {
        float p = (float)pos[bt];
        float fr = p * exp2f(-(float)tid * 0.20762050593045456f); // log2(1e4)/64
        float s, c;
        sincosf(fr, &s, &c);
        sss[tid] = s;
        scs[tid] = c;
    }
    __syncthreads();
    int e0 = tid << 3;
    int hh = e0 >> 7, d0 = e0 & 127;
    const u16* row = xin + (size_t)bt * instride + (hh << 7);
    u16 ov[8];
    if (d0 < 64) {
        const s16x8 x1 = *reinterpret_cast<const s16x8*>(row + d0);
        const s16x8 x2 = *reinterpret_cast<const s16x8*>(row + d0 + 64);
#pragma unroll
        for (int i = 0; i < 8; ++i) {
            int j = d0 + i;
            float v = bf2f((u16)x1[i]) * scs[j] - bf2f((u16)x2[i]) * sss[j];
            ov[i] = f2bf(v * scale);
        }
    } else {
        const s16x8 x1 = *reinterpret_cast<const s16x8*>(row + d0 - 64);
        const s16x8 x2 = *reinterpret_cast<const s16x8*>(row + d0);
#pragma unroll
        for (int i = 0; i < 8; ++i) {
            int j = d0 - 64 + i;
            float v = bf2f((u16)x1[i]) * sss[j] + bf2f((u16)x2[i]) * scs[j];
            ov[i] = f2bf(v * scale);
        }
    }
    u32 w0 = (u32)ov[0] | ((u32)ov[1] << 16);
    u32 w1 = (u32)ov[2] | ((u32)ov[3] << 16);
    u32 w2 = (u32)ov[4] | ((u32)ov[5] << 16);
    u32 w3 = (u32)ov[6] | ((u32)ov[7] << 16);
    u16* op = xout + ((size_t)(b * nH + hh) * 2048 + t) * 128 + d0;
    *reinterpret_cast<uint4*>(op) = make_uint4(w0, w1, w2, w3);
}

// ---------- V relayout: kvraw cols [512,1024) -> Vt (B*HKV, 128, T) ----------
__global__ __launch_bounds__(256) void k_vt(const u16* __restrict__ kvraw,
                                            u16* __restrict__ Vt) {
    __shared__ u16 lt[32][33];
    int t0 = blockIdx.x << 5, d0 = blockIdx.y << 5, bh = blockIdx.z;
    int b = bh >> 2, hk = bh & 3;
    int tid = threadIdx.x, rr = tid >> 5, cc = tid & 31;
#pragma unroll
    for (int j = 0; j < 4; ++j)
        lt[rr + j * 8][cc] =
            kvraw[(size_t)((b << 11) + t0 + rr + j * 8) * 1024 + 512 + (hk << 7) + d0 + cc];
    __syncthreads();
#pragma unroll
    for (int j = 0; j < 4; ++j)
        Vt[((size_t)(bh << 7) + d0 + rr + j * 8) * 2048 + t0 + cc] = lt[cc][rr + j * 8];
}

// ---------- causal GQA flash attention ----------
// Q: (B,16,T,128) bf16 (pre-scaled by 1/sqrt(128)*log2e), K: (B,4,T,128), Vt: (B*4,128,T)
// ctx out: (B*T, 2048) bf16, col = h*128+d
__global__ __launch_bounds__(256) void k_attn(const u16* __restrict__ Q,
                                              const u16* __restrict__ K,
                                              const u16* __restrict__ Vt,
                                              u16* __restrict__ ctx) {
    __shared__ u16 P_lds[4][32 * 32];
    const int tid = threadIdx.x;
    const int w = tid >> 6, l = tid & 63;
    const int lr = l & 15, lg = l >> 4;
    const int qb = blockIdx.x, bh = blockIdx.y;
    const int b = bh >> 4, h = bh & 15, hk = h >> 2;
    const int qw = (qb << 7) + (w << 5);  // wave's first q row
    const u16* Qg = Q + (size_t)(b * 16 + h) * 2048 * 128;
    const u16* Kg = K + (size_t)(b * 4 + hk) * 2048 * 128;
    const u16* Vg = Vt + (size_t)(b * 4 + hk) * 128 * 2048;
    s16x8 aq[2][4];
#pragma unroll
    for (int mf = 0; mf < 2; ++mf)
#pragma unroll
        for (int ks = 0; ks < 4; ++ks)
            aq[mf][ks] = *reinterpret_cast<const s16x8*>(
                Qg + (size_t)(qw + (mf << 4) + lr) * 128 + (ks << 5) + (lg << 3));
    f32x4 o[2][8] = {};
    float m_s[2][4], l_s[2][4];
#pragma unroll
    for (int mf = 0; mf < 2; ++mf)
#pragma unroll
        for (int r = 0; r < 4; ++r) {
            m_s[mf][r] = -1e30f;
            l_s[mf][r] = 0.f;
        }
    const int ntiles = (qw >> 5) + 1;
    u16* Pw = &P_lds[w][0];
    for (int t = 0; t < ntiles; ++t) {
        const int kv0 = t << 5;
        f32x4 s[2][2] = {};
#pragma unroll
        for (int ks = 0; ks < 4; ++ks) {
            s16x8 bk[2];
#pragma unroll
            for (int nf = 0; nf < 2; ++nf)
                bk[nf] = *reinterpret_cast<const s16x8*>(
                    Kg + (size_t)(kv0 + (nf << 4) + lr) * 128 + (ks << 5) + (lg << 3));
#pragma unroll
            for (int mf = 0; mf < 2; ++mf)
#pragma unroll
                for (int nf = 0; nf < 2; ++nf)
                    s[mf][nf] = mfma_bf16(aq[mf][ks], bk[nf], s[mf][nf]);
        }
        const bool notfull = (kv0 + 31) > qw;
#pragma unroll
        for (int mf = 0; mf < 2; ++mf) {
#pragma unroll
            for (int r = 0; r < 4; ++r) {
                int qrow = qw + (mf << 4) + (lg << 2) + r;
                if (notfull) {
                    if (kv0 + lr > qrow) s[mf][0][r] = -1e30f;
                    if (kv0 + 16 + lr > qrow) s[mf][1][r] = -1e30f;
                }
                float mx = fmaxf(s[mf][0][r], s[mf][1][r]);
                mx = fmaxf(mx, __shfl_xor(mx, 1));
                mx = fmaxf(mx, __shfl_xor(mx, 2));
                mx = fmaxf(mx, __shfl_xor(mx, 4));
                mx = fmaxf(mx, __shfl_xor(mx, 8));
                float mnew = fmaxf(m_s[mf][r], mx);
                float fac = exp2f(m_s[mf][r] - mnew);
                m_s[mf][r] = mnew;
                float p0 = exp2f(s[mf][0][r] - mnew);
                float p1 = exp2f(s[mf][1][r] - mnew);
                s[mf][0][r] = p0;
                s[mf][1][r] = p1;
                float rs = p0 + p1;
                rs += __shfl_xor(rs, 1);
                rs += __shfl_xor(rs, 2);
                rs += __shfl_xor(rs, 4);
                rs += __shfl_xor(rs, 8);
                l_s[mf][r] = l_s[mf][r] * fac + rs;
#pragma unroll
                for (int df = 0; df < 8; ++df) o[mf][df][r] *= fac;
            }
        }
        // stage P (D-layout -> A-layout) through per-wave LDS
#pragma unroll
        for (int mf = 0; mf < 2; ++mf)
#pragma unroll
            for (int r = 0; r < 4; ++r) {
                int prow = (mf << 4) + (lg << 2) + r;
                Pw[prow * 32 + lr] = f2bf(s[mf][0][r]);
                Pw[prow * 32 + 16 + lr] = f2bf(s[mf][1][r]);
            }
        asm volatile("s_waitcnt lgkmcnt(0)" ::: "memory");
        s16x8 ap[2];
#pragma unroll
        for (int mf = 0; mf < 2; ++mf)
            ap[mf] = *reinterpret_cast<const s16x8*>(&Pw[((mf << 4) + lr) * 32 + (lg << 3)]);
#pragma unroll
        for (int df = 0; df < 8; ++df) {
            s16x8 bv = *reinterpret_cast<const s16x8*>(
                Vg + (size_t)((df << 4) + lr) * 2048 + kv0 + (lg << 3));
#pragma unroll
            for (int mf = 0; mf < 2; ++mf) o[mf][df] = mfma_bf16(ap[mf], bv, o[mf][df]);
        }
    }
    // epilogue: divide by l, write ctx
#pragma unroll
    for (int mf = 0; mf < 2; ++mf) {
#pragma unroll
        for (int r = 0; r < 4; ++r) {
            float inv = 1.f / l_s[mf][r];
            int grow = (b << 11) + qw + (mf << 4) + (lg << 2) + r;
#pragma unroll
            for (int df = 0; df < 8; ++df)
                ctx[(size_t)grow * 2048 + (h << 7) + (df << 4) + lr] =
                    f2bf(o[mf][df][r] * inv);
        }
    }
}

// ---------- launch ----------
extern "C" void kernel_launch(void* const* d_in, const int* in_sizes, int n_in,
                              void* d_out, int out_size, void* d_ws, size_t ws_size,
                              hipStream_t stream) {
    const float* Xq = (const float*)d_in[0];
    const float* Xkv = (const float*)d_in[1];
    const float* Wq = (const float*)d_in[2];
    const float* Wk = (const float*)d_in[3];
    const float* Wv = (const float*)d_in[4];
    const float* Wo = (const float*)d_in[5];
    const int* qpos = (const int*)d_in[6];
    const int* kpos = (const int*)d_in[7];
    float* out = (float*)d_out;
    char* ws = (char*)d_ws;
    size_t off = 0;
    auto alloc = [&](size_t elems) {
        u16* p = (u16*)(ws + off);
        off += elems * 2;
        return p;
    };
    u16* XqB = alloc(8388608);   // (4096,2048) bf16
    u16* XkvB = alloc(8388608);  // (4096,2048)
    u16* WqT = alloc(4194304);   // (2048,2048)  N x K
    u16* WkvT = alloc(2097152);  // (1024,2048)  [K heads 0..511 | V heads 512..1023]
    u16* WoT = alloc(4194304);   // (2048,2048)
    u16* qraw = alloc(8388608);  // (4096,2048)
    u16* kvraw = alloc(4194304); // (4096,1024)
    u16* Qb = alloc(8388608);    // (B,16,T,128)
    u16* Kb = alloc(2097152);    // (B,4,T,128)
    u16* Vtb = alloc(2097152);   // (B*4,128,T)
    u16* ctxb = alloc(8388608);  // (4096,2048)

    k_cvt<<<2048, 256, 0, stream>>>(Xq, XqB, 2097152);
    k_cvt<<<2048, 256, 0, stream>>>(Xkv, XkvB, 2097152);
    k_tcvt<<<dim3(64, 64), 256, 0, stream>>>(Wq, WqT, 2048, 2048);
    k_tcvt<<<dim3(64, 16), 256, 0, stream>>>(Wk, WkvT, 2048, 512);
    k_tcvt<<<dim3(64, 16), 256, 0, stream>>>(Wv, WkvT + (size_t)512 * 2048, 2048, 512);
    k_tcvt<<<dim3(64, 64), 256, 0, stream>>>(Wo, WoT, 2048, 2048);
    k_gemm<1><<<dim3(32, 16), 256, 0, stream>>>(XqB, WqT, qraw, 4096, 2048, 2048);
    k_gemm<1><<<dim3(32, 8), 256, 0, stream>>>(XkvB, WkvT, kvraw, 4096, 1024, 2048);
    // scale = 1/sqrt(128) * log2(e) folded into Q for base-2 softmax
    k_rope<<<4096, 256, 0, stream>>>(qraw, 2048, qpos, Qb, 16, 0.12751741641f);
    k_rope<<<4096, 64, 0, stream>>>(kvraw, 1024, kpos, Kb, 4, 1.0f);
    k_vt<<<dim3(64, 4, 8), 256, 0, stream>>>(kvraw, Vtb);
    k_attn<<<dim3(16, 32), 256, 0, stream>>>(Qb, Kb, Vtb, ctxb);
    k_gemm<0><<<dim3(32, 16), 256, 0, stream>>>(ctxb, WoT, out, 4096, 2048, 2048);
}

// Round 3
// 499.248 us; speedup vs baseline: 1.0976x; 1.0976x over previous
//
#include <hip/hip_runtime.h>
#include <cstdint>
#include <cstddef>

typedef __attribute__((ext_vector_type(4))) float f32x4;
typedef __attribute__((ext_vector_type(8))) short s16x8;
typedef __attribute__((ext_vector_type(8))) __bf16 bf16x8;
typedef unsigned short u16;
typedef unsigned int u32;

#ifdef __has_builtin
#if __has_builtin(__builtin_amdgcn_global_load_lds)
#define HAVE_GLL 1
#endif
#endif
#ifndef HAVE_GLL
#define HAVE_GLL 0
#endif

// ---------- helpers ----------
__device__ __forceinline__ u16 f2bf(float f) {
    u32 u = __float_as_uint(f);
    u32 r = u + 0x7fffu + ((u >> 16) & 1u);   // RNE
    return (u16)(r >> 16);
}
__device__ __forceinline__ float bf2f(u16 u) {
    return __uint_as_float(((u32)u) << 16);
}
__device__ __forceinline__ f32x4 mfma_bf16(s16x8 a, s16x8 b, f32x4 c) {
    return __builtin_amdgcn_mfma_f32_16x16x32_bf16(
        __builtin_bit_cast(bf16x8, a), __builtin_bit_cast(bf16x8, b), c, 0, 0, 0);
}
// async global->LDS: per-lane global src g; LDS dest = uniform base + lane*16B
__device__ __forceinline__ void gll16(const u16* __restrict__ g, u16* lds, int l) {
#if HAVE_GLL
    __builtin_amdgcn_global_load_lds((const __attribute__((address_space(1))) u32*)g,
                                     (__attribute__((address_space(3))) u32*)lds, 16, 0, 0);
#else
    *reinterpret_cast<uint4*>(lds + (l << 3)) = *reinterpret_cast<const uint4*>(g);
#endif
}

// ---------- fp32 -> bf16 elementwise ----------
__global__ __launch_bounds__(256) void k_cvt(const float* __restrict__ in,
                                             u16* __restrict__ out, int n4) {
    int i = blockIdx.x * 256 + threadIdx.x;
    int stride = gridDim.x * 256;
    for (; i < n4; i += stride) {
        float4 v = reinterpret_cast<const float4*>(in)[i];
        u32 lo = (u32)f2bf(v.x) | ((u32)f2bf(v.y) << 16);
        u32 hi = (u32)f2bf(v.z) | ((u32)f2bf(v.w) << 16);
        reinterpret_cast<uint2*>(out)[i] = make_uint2(lo, hi);
    }
}

// ---------- transpose + convert: in (R,C) fp32 -> out (C,R) bf16 ----------
__global__ __launch_bounds__(256) void k_tcvt(const float* __restrict__ in,
                                              u16* __restrict__ out, int R, int C) {
    __shared__ float lt[32][33];
    int r0 = blockIdx.x << 5, c0 = blockIdx.y << 5;
    int tid = threadIdx.x, rr = tid >> 5, cc = tid & 31;
#pragma unroll
    for (int j = 0; j < 4; ++j)
        lt[rr + j * 8][cc] = in[(size_t)(r0 + rr + j * 8) * C + c0 + cc];
    __syncthreads();
#pragma unroll
    for (int j = 0; j < 4; ++j)
        out[(size_t)(c0 + rr + j * 8) * R + r0 + cc] = f2bf(lt[cc][rr + j * 8]);
}

// ---------- bf16 GEMM (m97 structure): A (M,K), Bt (N,K), C (M,N) ----------
// 128x128 tile, BK=64, 4 waves, global_load_lds staging, linear LDS.
template <int OUT_BF16>
__global__ __launch_bounds__(256) void k_gemm(const u16* __restrict__ A,
                                              const u16* __restrict__ Bt,
                                              void* __restrict__ Cv,
                                              int M, int N, int K) {
    __shared__ u16 sA[128 * 64];
    __shared__ u16 sB[128 * 64];
    const int tid = threadIdx.x;
    const int w = tid >> 6, l = tid & 63;
    const int m0 = blockIdx.x << 7, n0 = blockIdx.y << 7;
    const int wr = (w >> 1) << 6, wc = (w & 1) << 6;
    const int lr = l & 15, lg = l >> 4;
    const int crow = l >> 3, ccol = (l & 7) << 3;   // staging lane row/col
    f32x4 acc[4][4] = {};
    const int nkt = K >> 6;
    // chunk q = 4w+j covers tile rows [8q, 8q+8); lane l -> row 8q+(l>>3), col (l&7)*8
    const u16* pA = A + (size_t)(m0 + (w << 5) + crow) * K + ccol;
    const u16* pB = Bt + (size_t)(n0 + (w << 5) + crow) * K + ccol;
    for (int kt = 0; kt < nkt; ++kt) {
        const int k0 = kt << 6;
        __syncthreads();
#pragma unroll
        for (int j = 0; j < 4; ++j) {
            gll16(pA + (size_t)(j << 3) * K + k0, &sA[((w << 2) + j) << 9], l);
            gll16(pB + (size_t)(j << 3) * K + k0, &sB[((w << 2) + j) << 9], l);
        }
        __syncthreads();
#pragma unroll
        for (int ks = 0; ks < 2; ++ks) {
            s16x8 af[4], bfr[4];
#pragma unroll
            for (int i = 0; i < 4; ++i) {
                af[i] = *reinterpret_cast<const s16x8*>(
                    &sA[((wr + (i << 4) + lr) << 6) + (ks << 5) + (lg << 3)]);
                bfr[i] = *reinterpret_cast<const s16x8*>(
                    &sB[((wc + (i << 4) + lr) << 6) + (ks << 5) + (lg << 3)]);
            }
#pragma unroll
            for (int i = 0; i < 4; ++i)
#pragma unroll
                for (int jn = 0; jn < 4; ++jn)
                    acc[i][jn] = mfma_bf16(af[i], bfr[jn], acc[i][jn]);
        }
    }
#pragma unroll
    for (int i = 0; i < 4; ++i) {
        int rbase = m0 + wr + (i << 4) + (lg << 2);
#pragma unroll
        for (int jn = 0; jn < 4; ++jn) {
            int c = n0 + wc + (jn << 4) + lr;
#pragma unroll
            for (int r = 0; r < 4; ++r) {
                size_t idx = (size_t)(rbase + r) * N + c;
                if (OUT_BF16)
                    ((u16*)Cv)[idx] = f2bf(acc[i][jn][r]);
                else
                    ((float*)Cv)[idx] = acc[i][jn][r];
            }
        }
    }
}

// ---------- RoPE + head-major relayout ----------
__global__ void k_rope(const u16* __restrict__ xin, int instride,
                       const int* __restrict__ pos, u16* __restrict__ xout,
                       int nH, float scale) {
    __shared__ float scs[64], sss[64];
    int bt = blockIdx.x;
    int b = bt >> 11, t = bt & 2047;
    int tid = threadIdx.x;
    if (tid < 64) {
        float p = (float)pos[bt];
        float fr = p * exp2f(-(float)tid * 0.20762050593045456f); // log2(1e4)/64
        float s, c;
        sincosf(fr, &s, &c);
        sss[tid] = s;
        scs[tid] = c;
    }
    __syncthreads();
    int e0 = tid << 3;
    int hh = e0 >> 7, d0 = e0 & 127;
    const u16* row = xin + (size_t)bt * instride + (hh << 7);
    u16 ov[8];
    if (d0 < 64) {
        const s16x8 x1 = *reinterpret_cast<const s16x8*>(row + d0);
        const s16x8 x2 = *reinterpret_cast<const s16x8*>(row + d0 + 64);
#pragma unroll
        for (int i = 0; i < 8; ++i) {
            int j = d0 + i;
            float v = bf2f((u16)x1[i]) * scs[j] - bf2f((u16)x2[i]) * sss[j];
            ov[i] = f2bf(v * scale);
        }
    } else {
        const s16x8 x1 = *reinterpret_cast<const s16x8*>(row + d0 - 64);
        const s16x8 x2 = *reinterpret_cast<const s16x8*>(row + d0);
#pragma unroll
        for (int i = 0; i < 8; ++i) {
            int j = d0 - 64 + i;
            float v = bf2f((u16)x1[i]) * sss[j] + bf2f((u16)x2[i]) * scs[j];
            ov[i] = f2bf(v * scale);
        }
    }
    u32 w0 = (u32)ov[0] | ((u32)ov[1] << 16);
    u32 w1 = (u32)ov[2] | ((u32)ov[3] << 16);
    u32 w2 = (u32)ov[4] | ((u32)ov[5] << 16);
    u32 w3 = (u32)ov[6] | ((u32)ov[7] << 16);
    u16* op = xout + ((size_t)(b * nH + hh) * 2048 + t) * 128 + d0;
    *reinterpret_cast<uint4*>(op) = make_uint4(w0, w1, w2, w3);
}

// ---------- V relayout: kvraw cols [512,1024) -> Vt (B*HKV, 128, T) ----------
__global__ __launch_bounds__(256) void k_vt(const u16* __restrict__ kvraw,
                                            u16* __restrict__ Vt) {
    __shared__ u16 lt[32][33];
    int t0 = blockIdx.x << 5, d0 = blockIdx.y << 5, bh = blockIdx.z;
    int b = bh >> 2, hk = bh & 3;
    int tid = threadIdx.x, rr = tid >> 5, cc = tid & 31;
#pragma unroll
    for (int j = 0; j < 4; ++j)
        lt[rr + j * 8][cc] =
            kvraw[(size_t)((b << 11) + t0 + rr + j * 8) * 1024 + 512 + (hk << 7) + d0 + cc];
    __syncthreads();
#pragma unroll
    for (int j = 0; j < 4; ++j)
        Vt[((size_t)(bh << 7) + d0 + rr + j * 8) * 2048 + t0 + cc] = lt[cc][rr + j * 8];
}

// ---------- causal GQA flash attention, statically balanced ----------
// Wave owns 16 rows of strip pi (mf0) + 16 rows of strip 127-pi (mf1).
// Per-block: ntA = bx+1, ntB = 32-bx uniform -> every block costs 33 tile-units.
// K/V staged per-tile into LDS via global_load_lds with pre-swizzled source.
__global__ __launch_bounds__(256) void k_attn(const u16* __restrict__ Q,
                                              const u16* __restrict__ K,
                                              const u16* __restrict__ Vt,
                                              u16* __restrict__ ctx) {
    __shared__ u16 sK[64 * 128];       // 16 KB  (KV tile, swizzled slot^= row&15)
    __shared__ u16 sV[128 * 64];       // 16 KB  (d-major, swizzled slot^= row&7)
    __shared__ u16 P_all[4][32 * 64];  // 16 KB  per-wave P
    const int tid = threadIdx.x;
    const int w = tid >> 6, l = tid & 63;
    const int lr = l & 15, lg = l >> 4;
    const int bx = blockIdx.x, bh = blockIdx.y;
    const int b = bh >> 4, h = bh & 15, hk = h >> 2;
    const int pi = (bx << 2) + w;            // 0..63
    const int qlow = pi << 4;                // strip pi
    const int qhigh = (127 - pi) << 4;       // strip 127-pi
    const int ntA = bx + 1;                  // tiles for mf0 (uniform in block)
    const int ntB = 32 - bx;                 // tiles for mf1 (uniform in block)
    const u16* Qg = Q + (size_t)(b * 16 + h) * 2048 * 128;
    const u16* Kg = K + (size_t)(b * 4 + hk) * 2048 * 128;
    const u16* Vg = Vt + (size_t)(b * 4 + hk) * 128 * 2048;
    u16* Pw = &P_all[w][0];

    s16x8 aq[2][4];
#pragma unroll
    for (int ks = 0; ks < 4; ++ks) {
        aq[0][ks] = *reinterpret_cast<const s16x8*>(
            Qg + (size_t)(qlow + lr) * 128 + (ks << 5) + (lg << 3));
        aq[1][ks] = *reinterpret_cast<const s16x8*>(
            Qg + (size_t)(qhigh + lr) * 128 + (ks << 5) + (lg << 3));
    }
    f32x4 o[2][8] = {};
    float m_s[2][4], l_s[2][4];
#pragma unroll
    for (int mf = 0; mf < 2; ++mf)
#pragma unroll
        for (int r = 0; r < 4; ++r) {
            m_s[mf][r] = -1e30f;
            l_s[mf][r] = 0.f;
        }
    // staging lane geometry
    const int kcrow = l >> 4, kslot = (l & 15);          // K chunk: 4 rows x 16 slots
    const int vcrow = l >> 3, vslot = (l & 7);           // V chunk: 8 rows x 8 slots

    for (int t = 0; t < ntB; ++t) {
        const int kv0 = t << 6;
        const bool mf0on = (t < ntA);
        const int mflo = mf0on ? 0 : 1;
        __syncthreads();
        // stage K (16 chunks of 4 rows) and V (16 chunks of 8 rows), 4 each per wave
#pragma unroll
        for (int j = 0; j < 4; ++j) {
            int q = (w << 2) + j;
            int krow = (q << 2) + kcrow;                 // 0..63
            int kgs = kslot ^ (krow & 15);               // pre-swizzled source slot
            gll16(Kg + (size_t)(kv0 + krow) * 128 + (kgs << 3), &sK[q << 9], l);
            int vrow = (q << 3) + vcrow;                 // 0..127
            int vgs = vslot ^ (vrow & 7);
            gll16(Vg + (size_t)vrow * 2048 + kv0 + (vgs << 3), &sV[q << 9], l);
        }
        __syncthreads();
        // QK^T
        f32x4 s[2][4] = {};
#pragma unroll
        for (int ks = 0; ks < 4; ++ks) {
            s16x8 bk[4];
#pragma unroll
            for (int nf = 0; nf < 4; ++nf) {
                int rk = (nf << 4) + lr;
                int slot = ((ks << 2) + lg) ^ (rk & 15);
                bk[nf] = *reinterpret_cast<const s16x8*>(&sK[(rk << 7) + (slot << 3)]);
            }
            __builtin_amdgcn_s_setprio(1);
            if (mf0on) {
#pragma unroll
                for (int nf = 0; nf < 4; ++nf)
                    s[0][nf] = mfma_bf16(aq[0][ks], bk[nf], s[0][nf]);
            }
#pragma unroll
            for (int nf = 0; nf < 4; ++nf)
                s[1][nf] = mfma_bf16(aq[1][ks], bk[nf], s[1][nf]);
            __builtin_amdgcn_s_setprio(0);
        }
        // causal mask (last tile of each mf only)
#pragma unroll
        for (int mf = 0; mf < 2; ++mf) {
            if (mf < mflo) continue;
            int ntm = mf ? ntB : ntA;
            if (t == ntm - 1) {
                int qb_ = mf ? qhigh : qlow;
#pragma unroll
                for (int nf = 0; nf < 4; ++nf) {
                    int col = kv0 + (nf << 4) + lr;
#pragma unroll
                    for (int r = 0; r < 4; ++r)
                        if (col > qb_ + (lg << 2) + r) s[mf][nf][r] = -3.0e38f;
                }
            }
        }
        // row max + defer-max decision
        float pmax[2][4];
        int ok = 1;
#pragma unroll
        for (int mf = 0; mf < 2; ++mf) {
            if (mf < mflo) continue;
#pragma unroll
            for (int r = 0; r < 4; ++r) {
                float mx = fmaxf(fmaxf(s[mf][0][r], s[mf][1][r]),
                                 fmaxf(s[mf][2][r], s[mf][3][r]));
                mx = fmaxf(mx, __shfl_xor(mx, 1));
                mx = fmaxf(mx, __shfl_xor(mx, 2));
                mx = fmaxf(mx, __shfl_xor(mx, 4));
                mx = fmaxf(mx, __shfl_xor(mx, 8));
                pmax[mf][r] = mx;
                ok &= (mx <= m_s[mf][r] + 8.0f) ? 1 : 0;
            }
        }
        if (!__all(ok)) {
#pragma unroll
            for (int mf = 0; mf < 2; ++mf) {
                if (mf < mflo) continue;
#pragma unroll
                for (int r = 0; r < 4; ++r) {
                    float mnew = fmaxf(m_s[mf][r], pmax[mf][r]);
                    float fac = exp2f(m_s[mf][r] - mnew);
                    m_s[mf][r] = mnew;
                    l_s[mf][r] *= fac;
#pragma unroll
                    for (int df = 0; df < 8; ++df) o[mf][df][r] *= fac;
                }
            }
        }
        // exp, stage P (swizzled), row-sum
#pragma unroll
        for (int mf = 0; mf < 2; ++mf) {
            if (mf < mflo) continue;
#pragma unroll
            for (int r = 0; r < 4; ++r) {
                int prow = (mf << 4) + (lg << 2) + r;
                int ro = prow << 6, sw = (prow & 7) << 3;
                float rs = 0.f;
#pragma unroll
                for (int nf = 0; nf < 4; ++nf) {
                    float pv = exp2f(s[mf][nf][r] - m_s[mf][r]);
                    rs += pv;
                    Pw[ro + ((lr + (nf << 4)) ^ sw)] = f2bf(pv);
                }
                rs += __shfl_xor(rs, 1);
                rs += __shfl_xor(rs, 2);
                rs += __shfl_xor(rs, 4);
                rs += __shfl_xor(rs, 8);
                l_s[mf][r] += rs;
            }
        }
        asm volatile("s_waitcnt lgkmcnt(0)" ::: "memory");
        // PV
#pragma unroll
        for (int ks2 = 0; ks2 < 2; ++ks2) {
            int pslot = (((ks2 << 2) + lg) ^ (lr & 7)) << 3;
            s16x8 ap1 = *reinterpret_cast<const s16x8*>(&Pw[((16 + lr) << 6) + pslot]);
            s16x8 ap0;
            if (mf0on)
                ap0 = *reinterpret_cast<const s16x8*>(&Pw[(lr << 6) + pslot]);
            s16x8 bv[8];
#pragma unroll
            for (int df = 0; df < 8; ++df) {
                int rv = (df << 4) + lr;
                int slot = ((ks2 << 2) + lg) ^ (rv & 7);
                bv[df] = *reinterpret_cast<const s16x8*>(&sV[(rv << 6) + (slot << 3)]);
            }
            __builtin_amdgcn_s_setprio(1);
#pragma unroll
            for (int df = 0; df < 8; ++df) {
                o[1][df] = mfma_bf16(ap1, bv[df], o[1][df]);
                if (mf0on) o[0][df] = mfma_bf16(ap0, bv[df], o[0][df]);
            }
            __builtin_amdgcn_s_setprio(0);
        }
    }
    // epilogue
#pragma unroll
    for (int mf = 0; mf < 2; ++mf) {
        int qb_ = mf ? qhigh : qlow;
#pragma unroll
        for (int r = 0; r < 4; ++r) {
            float inv = 1.f / l_s[mf][r];
            int grow = (b << 11) + qb_ + (lg << 2) + r;
#pragma unroll
            for (int df = 0; df < 8; ++df)
                ctx[(size_t)grow * 2048 + (h << 7) + (df << 4) + lr] =
                    f2bf(o[mf][df][r] * inv);
        }
    }
}

// ---------- launch ----------
extern "C" void kernel_launch(void* const* d_in, const int* in_sizes, int n_in,
                              void* d_out, int out_size, void* d_ws, size_t ws_size,
                              hipStream_t stream) {
    const float* Xq = (const float*)d_in[0];
    const float* Xkv = (const float*)d_in[1];
    const float* Wq = (const float*)d_in[2];
    const float* Wk = (const float*)d_in[3];
    const float* Wv = (const float*)d_in[4];
    const float* Wo = (const float*)d_in[5];
    const int* qpos = (const int*)d_in[6];
    const int* kpos = (const int*)d_in[7];
    float* out = (float*)d_out;
    char* ws = (char*)d_ws;
    size_t off = 0;
    auto alloc = [&](size_t elems) {
        u16* p = (u16*)(ws + off);
        off += elems * 2;
        return p;
    };
    u16* XqB = alloc(8388608);   // (4096,2048) bf16
    u16* XkvB = alloc(8388608);  // (4096,2048)
    u16* WqT = alloc(4194304);   // (2048,2048)  N x K
    u16* WkvT = alloc(2097152);  // (1024,2048)  [K | V]
    u16* WoT = alloc(4194304);   // (2048,2048)
    u16* qraw = alloc(8388608);  // (4096,2048)
    u16* kvraw = alloc(4194304); // (4096,1024)
    u16* Qb = alloc(8388608);    // (B,16,T,128)
    u16* Kb = alloc(2097152);    // (B,4,T,128)
    u16* Vtb = alloc(2097152);   // (B*4,128,T)
    u16* ctxb = alloc(8388608);  // (4096,2048)

    k_cvt<<<2048, 256, 0, stream>>>(Xq, XqB, 2097152);
    k_cvt<<<2048, 256, 0, stream>>>(Xkv, XkvB, 2097152);
    k_tcvt<<<dim3(64, 64), 256, 0, stream>>>(Wq, WqT, 2048, 2048);
    k_tcvt<<<dim3(64, 16), 256, 0, stream>>>(Wk, WkvT, 2048, 512);
    k_tcvt<<<dim3(64, 16), 256, 0, stream>>>(Wv, WkvT + (size_t)512 * 2048, 2048, 512);
    k_tcvt<<<dim3(64, 64), 256, 0, stream>>>(Wo, WoT, 2048, 2048);
    k_gemm<1><<<dim3(32, 16), 256, 0, stream>>>(XqB, WqT, qraw, 4096, 2048, 2048);
    k_gemm<1><<<dim3(32, 8), 256, 0, stream>>>(XkvB, WkvT, kvraw, 4096, 1024, 2048);
    // scale = 1/sqrt(128) * log2(e) folded into Q for base-2 softmax
    k_rope<<<4096, 256, 0, stream>>>(qraw, 2048, qpos, Qb, 16, 0.12751741641f);
    k_rope<<<4096, 64, 0, stream>>>(kvraw, 1024, kpos, Kb, 4, 1.0f);
    k_vt<<<dim3(64, 4, 8), 256, 0, stream>>>(kvraw, Vtb);
    k_attn<<<dim3(16, 32), 256, 0, stream>>>(Qb, Kb, Vtb, ctxb);
    k_gemm<0><<<dim3(32, 16), 256, 0, stream>>>(ctxb, WoT, out, 4096, 2048, 2048);
}

// Round 4
// 487.989 us; speedup vs baseline: 1.1229x; 1.0231x over previous
//
#include <hip/hip_runtime.h>
#include <cstdint>
#include <cstddef>

typedef __attribute__((ext_vector_type(4))) float f32x4;
typedef __attribute__((ext_vector_type(8))) short s16x8;
typedef __attribute__((ext_vector_type(8))) __bf16 bf16x8;
typedef unsigned short u16;
typedef unsigned int u32;

#ifdef __has_builtin
#if __has_builtin(__builtin_amdgcn_global_load_lds)
#define HAVE_GLL 1
#endif
#endif
#ifndef HAVE_GLL
#define HAVE_GLL 0
#endif

// ---------- helpers ----------
__device__ __forceinline__ u16 f2bf(float f) {
    u32 u = __float_as_uint(f);
    u32 r = u + 0x7fffu + ((u >> 16) & 1u);   // RNE
    return (u16)(r >> 16);
}
__device__ __forceinline__ float bf2f(u16 u) {
    return __uint_as_float(((u32)u) << 16);
}
__device__ __forceinline__ f32x4 mfma_bf16(s16x8 a, s16x8 b, f32x4 c) {
    return __builtin_amdgcn_mfma_f32_16x16x32_bf16(
        __builtin_bit_cast(bf16x8, a), __builtin_bit_cast(bf16x8, b), c, 0, 0, 0);
}
// async global->LDS: per-lane global src g; LDS dest = uniform base + lane*16B
__device__ __forceinline__ void gll16(const u16* __restrict__ g, u16* lds, int l) {
#if HAVE_GLL
    __builtin_amdgcn_global_load_lds((const __attribute__((address_space(1))) u32*)g,
                                     (__attribute__((address_space(3))) u32*)lds, 16, 0, 0);
#else
    *reinterpret_cast<uint4*>(lds + (l << 3)) = *reinterpret_cast<const uint4*>(g);
#endif
}

// ---------- fp32 -> bf16 elementwise ----------
__global__ __launch_bounds__(256) void k_cvt(const float* __restrict__ in,
                                             u16* __restrict__ out, int n4) {
    int i = blockIdx.x * 256 + threadIdx.x;
    int stride = gridDim.x * 256;
    for (; i < n4; i += stride) {
        float4 v = reinterpret_cast<const float4*>(in)[i];
        u32 lo = (u32)f2bf(v.x) | ((u32)f2bf(v.y) << 16);
        u32 hi = (u32)f2bf(v.z) | ((u32)f2bf(v.w) << 16);
        reinterpret_cast<uint2*>(out)[i] = make_uint2(lo, hi);
    }
}

// ---------- transpose + convert: in (R,C) fp32 -> out (C,R) bf16 ----------
__global__ __launch_bounds__(256) void k_tcvt(const float* __restrict__ in,
                                              u16* __restrict__ out, int R, int C) {
    __shared__ float lt[32][33];
    int r0 = blockIdx.x << 5, c0 = blockIdx.y << 5;
    int tid = threadIdx.x, rr = tid >> 5, cc = tid & 31;
#pragma unroll
    for (int j = 0; j < 4; ++j)
        lt[rr + j * 8][cc] = in[(size_t)(r0 + rr + j * 8) * C + c0 + cc];
    __syncthreads();
#pragma unroll
    for (int j = 0; j < 4; ++j)
        out[(size_t)(c0 + rr + j * 8) * R + r0 + cc] = f2bf(lt[cc][rr + j * 8]);
}

// ---------- bf16 GEMM (m97 structure): A (M,K), Bt (N,K), C (M,N) ----------
// 128x128 tile, BK=64, 4 waves, global_load_lds staging, linear LDS.
template <int OUT_BF16>
__global__ __launch_bounds__(256) void k_gemm(const u16* __restrict__ A,
                                              const u16* __restrict__ Bt,
                                              void* __restrict__ Cv,
                                              int M, int N, int K) {
    __shared__ u16 sA[128 * 64];
    __shared__ u16 sB[128 * 64];
    const int tid = threadIdx.x;
    const int w = tid >> 6, l = tid & 63;
    const int m0 = blockIdx.x << 7, n0 = blockIdx.y << 7;
    const int wr = (w >> 1) << 6, wc = (w & 1) << 6;
    const int lr = l & 15, lg = l >> 4;
    const int crow = l >> 3, ccol = (l & 7) << 3;   // staging lane row/col
    f32x4 acc[4][4] = {};
    const int nkt = K >> 6;
    const u16* pA = A + (size_t)(m0 + (w << 5) + crow) * K + ccol;
    const u16* pB = Bt + (size_t)(n0 + (w << 5) + crow) * K + ccol;
    for (int kt = 0; kt < nkt; ++kt) {
        const int k0 = kt << 6;
        __syncthreads();
#pragma unroll
        for (int j = 0; j < 4; ++j) {
            gll16(pA + (size_t)(j << 3) * K + k0, &sA[((w << 2) + j) << 9], l);
            gll16(pB + (size_t)(j << 3) * K + k0, &sB[((w << 2) + j) << 9], l);
        }
        __syncthreads();
#pragma unroll
        for (int ks = 0; ks < 2; ++ks) {
            s16x8 af[4], bfr[4];
#pragma unroll
            for (int i = 0; i < 4; ++i) {
                af[i] = *reinterpret_cast<const s16x8*>(
                    &sA[((wr + (i << 4) + lr) << 6) + (ks << 5) + (lg << 3)]);
                bfr[i] = *reinterpret_cast<const s16x8*>(
                    &sB[((wc + (i << 4) + lr) << 6) + (ks << 5) + (lg << 3)]);
            }
#pragma unroll
            for (int i = 0; i < 4; ++i)
#pragma unroll
                for (int jn = 0; jn < 4; ++jn)
                    acc[i][jn] = mfma_bf16(af[i], bfr[jn], acc[i][jn]);
        }
    }
#pragma unroll
    for (int i = 0; i < 4; ++i) {
        int rbase = m0 + wr + (i << 4) + (lg << 2);
#pragma unroll
        for (int jn = 0; jn < 4; ++jn) {
            int c = n0 + wc + (jn << 4) + lr;
#pragma unroll
            for (int r = 0; r < 4; ++r) {
                size_t idx = (size_t)(rbase + r) * N + c;
                if (OUT_BF16)
                    ((u16*)Cv)[idx] = f2bf(acc[i][jn][r]);
                else
                    ((float*)Cv)[idx] = acc[i][jn][r];
            }
        }
    }
}

// ---------- RoPE + head-major relayout ----------
__global__ void k_rope(const u16* __restrict__ xin, int instride,
                       const int* __restrict__ pos, u16* __restrict__ xout,
                       int nH, float scale) {
    __shared__ float scs[64], sss[64];
    int bt = blockIdx.x;
    int b = bt >> 11, t = bt & 2047;
    int tid = threadIdx.x;
    if (tid < 64) {
        float p = (float)pos[bt];
        float fr = p * exp2f(-(float)tid * 0.20762050593045456f); // log2(1e4)/64
        float s, c;
        sincosf(fr, &s, &c);
        sss[tid] = s;
        scs[tid] = c;
    }
    __syncthreads();
    int e0 = tid << 3;
    int hh = e0 >> 7, d0 = e0 & 127;
    const u16* row = xin + (size_t)bt * instride + (hh << 7);
    u16 ov[8];
    if (d0 < 64) {
        const s16x8 x1 = *reinterpret_cast<const s16x8*>(row + d0);
        const s16x8 x2 = *reinterpret_cast<const s16x8*>(row + d0 + 64);
#pragma unroll
        for (int i = 0; i < 8; ++i) {
            int j = d0 + i;
            float v = bf2f((u16)x1[i]) * scs[j] - bf2f((u16)x2[i]) * sss[j];
            ov[i] = f2bf(v * scale);
        }
    } else {
        const s16x8 x1 = *reinterpret_cast<const s16x8*>(row + d0 - 64);
        const s16x8 x2 = *reinterpret_cast<const s16x8*>(row + d0);
#pragma unroll
        for (int i = 0; i < 8; ++i) {
            int j = d0 - 64 + i;
            float v = bf2f((u16)x1[i]) * sss[j] + bf2f((u16)x2[i]) * scs[j];
            ov[i] = f2bf(v * scale);
        }
    }
    u32 w0 = (u32)ov[0] | ((u32)ov[1] << 16);
    u32 w1 = (u32)ov[2] | ((u32)ov[3] << 16);
    u32 w2 = (u32)ov[4] | ((u32)ov[5] << 16);
    u32 w3 = (u32)ov[6] | ((u32)ov[7] << 16);
    u16* op = xout + ((size_t)(b * nH + hh) * 2048 + t) * 128 + d0;
    *reinterpret_cast<uint4*>(op) = make_uint4(w0, w1, w2, w3);
}

// ---------- V relayout: kvraw cols [512,1024) -> Vt (B*HKV, 128, T) ----------
__global__ __launch_bounds__(256) void k_vt(const u16* __restrict__ kvraw,
                                            u16* __restrict__ Vt) {
    __shared__ u16 lt[32][33];
    int t0 = blockIdx.x << 5, d0 = blockIdx.y << 5, bh = blockIdx.z;
    int b = bh >> 2, hk = bh & 3;
    int tid = threadIdx.x, rr = tid >> 5, cc = tid & 31;
#pragma unroll
    for (int j = 0; j < 4; ++j)
        lt[rr + j * 8][cc] =
            kvraw[(size_t)((b << 11) + t0 + rr + j * 8) * 1024 + 512 + (hk << 7) + d0 + cc];
    __syncthreads();
#pragma unroll
    for (int j = 0; j < 4; ++j)
        Vt[((size_t)(bh << 7) + d0 + rr + j * 8) * 2048 + t0 + cc] = lt[cc][rr + j * 8];
}

// ---------- causal GQA flash attention: balanced strips + 2-phase K/V pipeline ----------
// Wave owns 16 rows of strip pi (mf0) + 16 rows of strip 127-pi (mf1);
// ntA=bx+1, ntB=32-bx uniform per block -> perfect static balance (33 units/block).
// Double-buffered K/V LDS: STAGE(t+1) issued before compute(t); ONE barrier/tile.
__global__ __launch_bounds__(256) void k_attn(const u16* __restrict__ Q,
                                              const u16* __restrict__ K,
                                              const u16* __restrict__ Vt,
                                              u16* __restrict__ ctx) {
    __shared__ u16 sK[2][64 * 128];    // 2 x 16 KB, swizzled slot ^= row&15
    __shared__ u16 sV[2][128 * 64];    // 2 x 16 KB, d-major, swizzled slot ^= row&7
    __shared__ u16 P_all[4][32 * 64];  // 16 KB per-wave P
    const int tid = threadIdx.x;
    const int w = tid >> 6, l = tid & 63;
    const int lr = l & 15, lg = l >> 4;
    const int bx = blockIdx.x, bh = blockIdx.y;
    const int b = bh >> 4, h = bh & 15, hk = h >> 2;
    const int pi = (bx << 2) + w;            // 0..63
    const int qlow = pi << 4;                // strip pi
    const int qhigh = (127 - pi) << 4;       // strip 127-pi
    const int ntA = bx + 1;                  // tiles for mf0 (uniform in block)
    const int ntB = 32 - bx;                 // tiles for mf1 (uniform in block)
    const u16* Qg = Q + (size_t)(b * 16 + h) * 2048 * 128;
    const u16* Kg = K + (size_t)(b * 4 + hk) * 2048 * 128;
    const u16* Vg = Vt + (size_t)(b * 4 + hk) * 128 * 2048;
    u16* Pw = &P_all[w][0];

    s16x8 aq[2][4];
#pragma unroll
    for (int ks = 0; ks < 4; ++ks) {
        aq[0][ks] = *reinterpret_cast<const s16x8*>(
            Qg + (size_t)(qlow + lr) * 128 + (ks << 5) + (lg << 3));
        aq[1][ks] = *reinterpret_cast<const s16x8*>(
            Qg + (size_t)(qhigh + lr) * 128 + (ks << 5) + (lg << 3));
    }
    f32x4 o[2][8] = {};
    float m_s[2][4], l_s[2][4];
#pragma unroll
    for (int mf = 0; mf < 2; ++mf)
#pragma unroll
        for (int r = 0; r < 4; ++r) {
            m_s[mf][r] = -1e30f;
            l_s[mf][r] = 0.f;
        }
    // staging lane geometry
    const int kcrow = l >> 4, kslot = (l & 15);          // K chunk: 4 rows x 16 slots
    const int vcrow = l >> 3, vslot = (l & 7);           // V chunk: 8 rows x 8 slots
    auto STAGE = [&](int t, int buf) {
#pragma unroll
        for (int j = 0; j < 4; ++j) {
            int q = (w << 2) + j;
            int krow = (q << 2) + kcrow;                 // 0..63
            int kgs = kslot ^ (krow & 15);               // pre-swizzled source slot
            gll16(Kg + (size_t)((t << 6) + krow) * 128 + (kgs << 3), &sK[buf][q << 9], l);
            int vrow = (q << 3) + vcrow;                 // 0..127
            int vgs = vslot ^ (vrow & 7);
            gll16(Vg + (size_t)vrow * 2048 + (t << 6) + (vgs << 3), &sV[buf][q << 9], l);
        }
    };

    STAGE(0, 0);
    __syncthreads();           // drain prologue staging
    int cur = 0;
    for (int t = 0; t < ntB; ++t) {
        // prefetch next tile into the other buffer; latency hides under compute
        if (t + 1 < ntB) STAGE(t + 1, cur ^ 1);
        const int kv0 = t << 6;
        const bool mf0on = (t < ntA);
        const int mflo = mf0on ? 0 : 1;
        // QK^T from sK[cur]
        f32x4 s[2][4] = {};
#pragma unroll
        for (int ks = 0; ks < 4; ++ks) {
            s16x8 bk[4];
#pragma unroll
            for (int nf = 0; nf < 4; ++nf) {
                int rk = (nf << 4) + lr;
                int slot = ((ks << 2) + lg) ^ (rk & 15);
                bk[nf] = *reinterpret_cast<const s16x8*>(&sK[cur][(rk << 7) + (slot << 3)]);
            }
            __builtin_amdgcn_s_setprio(1);
            if (mf0on) {
#pragma unroll
                for (int nf = 0; nf < 4; ++nf)
                    s[0][nf] = mfma_bf16(aq[0][ks], bk[nf], s[0][nf]);
            }
#pragma unroll
            for (int nf = 0; nf < 4; ++nf)
                s[1][nf] = mfma_bf16(aq[1][ks], bk[nf], s[1][nf]);
            __builtin_amdgcn_s_setprio(0);
        }
        // causal mask (last tile of each mf only)
#pragma unroll
        for (int mf = 0; mf < 2; ++mf) {
            if (mf < mflo) continue;
            int ntm = mf ? ntB : ntA;
            if (t == ntm - 1) {
                int qb_ = mf ? qhigh : qlow;
#pragma unroll
                for (int nf = 0; nf < 4; ++nf) {
                    int col = kv0 + (nf << 4) + lr;
#pragma unroll
                    for (int r = 0; r < 4; ++r)
                        if (col > qb_ + (lg << 2) + r) s[mf][nf][r] = -3.0e38f;
                }
            }
        }
        // row max + defer-max decision
        float pmax[2][4];
        int ok = 1;
#pragma unroll
        for (int mf = 0; mf < 2; ++mf) {
            if (mf < mflo) continue;
#pragma unroll
            for (int r = 0; r < 4; ++r) {
                float mx = fmaxf(fmaxf(s[mf][0][r], s[mf][1][r]),
                                 fmaxf(s[mf][2][r], s[mf][3][r]));
                mx = fmaxf(mx, __shfl_xor(mx, 1));
                mx = fmaxf(mx, __shfl_xor(mx, 2));
                mx = fmaxf(mx, __shfl_xor(mx, 4));
                mx = fmaxf(mx, __shfl_xor(mx, 8));
                pmax[mf][r] = mx;
                ok &= (mx <= m_s[mf][r] + 8.0f) ? 1 : 0;
            }
        }
        if (!__all(ok)) {
#pragma unroll
            for (int mf = 0; mf < 2; ++mf) {
                if (mf < mflo) continue;
#pragma unroll
                for (int r = 0; r < 4; ++r) {
                    float mnew = fmaxf(m_s[mf][r], pmax[mf][r]);
                    float fac = exp2f(m_s[mf][r] - mnew);
                    m_s[mf][r] = mnew;
                    l_s[mf][r] *= fac;
#pragma unroll
                    for (int df = 0; df < 8; ++df) o[mf][df][r] *= fac;
                }
            }
        }
        // exp, stage P (swizzled), row-sum
#pragma unroll
        for (int mf = 0; mf < 2; ++mf) {
            if (mf < mflo) continue;
#pragma unroll
            for (int r = 0; r < 4; ++r) {
                int prow = (mf << 4) + (lg << 2) + r;
                int ro = prow << 6, sw = (prow & 7) << 3;
                float rs = 0.f;
#pragma unroll
                for (int nf = 0; nf < 4; ++nf) {
                    float pv = exp2f(s[mf][nf][r] - m_s[mf][r]);
                    rs += pv;
                    Pw[ro + ((lr + (nf << 4)) ^ sw)] = f2bf(pv);
                }
                rs += __shfl_xor(rs, 1);
                rs += __shfl_xor(rs, 2);
                rs += __shfl_xor(rs, 4);
                rs += __shfl_xor(rs, 8);
                l_s[mf][r] += rs;
            }
        }
        asm volatile("s_waitcnt lgkmcnt(0)" ::: "memory");
        // PV from sV[cur]
#pragma unroll
        for (int ks2 = 0; ks2 < 2; ++ks2) {
            int pslot = (((ks2 << 2) + lg) ^ (lr & 7)) << 3;
            s16x8 ap1 = *reinterpret_cast<const s16x8*>(&Pw[((16 + lr) << 6) + pslot]);
            s16x8 ap0;
            if (mf0on)
                ap0 = *reinterpret_cast<const s16x8*>(&Pw[(lr << 6) + pslot]);
            s16x8 bv[8];
#pragma unroll
            for (int df = 0; df < 8; ++df) {
                int rv = (df << 4) + lr;
                int slot = ((ks2 << 2) + lg) ^ (rv & 7);
                bv[df] = *reinterpret_cast<const s16x8*>(&sV[cur][(rv << 6) + (slot << 3)]);
            }
            __builtin_amdgcn_s_setprio(1);
#pragma unroll
            for (int df = 0; df < 8; ++df) {
                o[1][df] = mfma_bf16(ap1, bv[df], o[1][df]);
                if (mf0on) o[0][df] = mfma_bf16(ap0, bv[df], o[0][df]);
            }
            __builtin_amdgcn_s_setprio(0);
        }
        __syncthreads();       // one barrier/tile: drains prefetch vmcnt + lgkm
        cur ^= 1;
    }
    // epilogue
#pragma unroll
    for (int mf = 0; mf < 2; ++mf) {
        int qb_ = mf ? qhigh : qlow;
#pragma unroll
        for (int r = 0; r < 4; ++r) {
            float inv = 1.f / l_s[mf][r];
            int grow = (b << 11) + qb_ + (lg << 2) + r;
#pragma unroll
            for (int df = 0; df < 8; ++df)
                ctx[(size_t)grow * 2048 + (h << 7) + (df << 4) + lr] =
                    f2bf(o[mf][df][r] * inv);
        }
    }
}

// ---------- launch ----------
extern "C" void kernel_launch(void* const* d_in, const int* in_sizes, int n_in,
                              void* d_out, int out_size, void* d_ws, size_t ws_size,
                              hipStream_t stream) {
    const float* Xq = (const float*)d_in[0];
    const float* Xkv = (const float*)d_in[1];
    const float* Wq = (const float*)d_in[2];
    const float* Wk = (const float*)d_in[3];
    const float* Wv = (const float*)d_in[4];
    const float* Wo = (const float*)d_in[5];
    const int* qpos = (const int*)d_in[6];
    const int* kpos = (const int*)d_in[7];
    float* out = (float*)d_out;
    char* ws = (char*)d_ws;
    size_t off = 0;
    auto alloc = [&](size_t elems) {
        u16* p = (u16*)(ws + off);
        off += elems * 2;
        return p;
    };
    u16* XqB = alloc(8388608);   // (4096,2048) bf16
    u16* XkvB = alloc(8388608);  // (4096,2048)
    u16* WqT = alloc(4194304);   // (2048,2048)  N x K
    u16* WkvT = alloc(2097152);  // (1024,2048)  [K | V]
    u16* WoT = alloc(4194304);   // (2048,2048)
    u16* qraw = alloc(8388608);  // (4096,2048)
    u16* kvraw = alloc(4194304); // (4096,1024)
    u16* Qb = alloc(8388608);    // (B,16,T,128)
    u16* Kb = alloc(2097152);    // (B,4,T,128)
    u16* Vtb = alloc(2097152);   // (B*4,128,T)
    u16* ctxb = alloc(8388608);  // (4096,2048)

    k_cvt<<<2048, 256, 0, stream>>>(Xq, XqB, 2097152);
    k_cvt<<<2048, 256, 0, stream>>>(Xkv, XkvB, 2097152);
    k_tcvt<<<dim3(64, 64), 256, 0, stream>>>(Wq, WqT, 2048, 2048);
    k_tcvt<<<dim3(64, 16), 256, 0, stream>>>(Wk, WkvT, 2048, 512);
    k_tcvt<<<dim3(64, 16), 256, 0, stream>>>(Wv, WkvT + (size_t)512 * 2048, 2048, 512);
    k_tcvt<<<dim3(64, 64), 256, 0, stream>>>(Wo, WoT, 2048, 2048);
    k_gemm<1><<<dim3(32, 16), 256, 0, stream>>>(XqB, WqT, qraw, 4096, 2048, 2048);
    k_gemm<1><<<dim3(32, 8), 256, 0, stream>>>(XkvB, WkvT, kvraw, 4096, 1024, 2048);
    // scale = 1/sqrt(128) * log2(e) folded into Q for base-2 softmax
    k_rope<<<4096, 256, 0, stream>>>(qraw, 2048, qpos, Qb, 16, 0.12751741641f);
    k_rope<<<4096, 64, 0, stream>>>(kvraw, 1024, kpos, Kb, 4, 1.0f);
    k_vt<<<dim3(64, 4, 8), 256, 0, stream>>>(kvraw, Vtb);
    k_attn<<<dim3(16, 32), 256, 0, stream>>>(Qb, Kb, Vtb, ctxb);
    k_gemm<0><<<dim3(32, 16), 256, 0, stream>>>(ctxb, WoT, out, 4096, 2048, 2048);
}

// Round 7
// 408.341 us; speedup vs baseline: 1.3420x; 1.1951x over previous
//
#include <hip/hip_runtime.h>
#include <cstdint>
#include <cstddef>

typedef __attribute__((ext_vector_type(4))) float f32x4;
typedef __attribute__((ext_vector_type(16))) float f32x16;
typedef __attribute__((ext_vector_type(8))) short s16x8;
typedef __attribute__((ext_vector_type(8))) __bf16 bf16x8;
typedef __attribute__((ext_vector_type(4))) unsigned int u32x4;
typedef unsigned short u16;
typedef unsigned int u32;

#ifdef __has_builtin
#if __has_builtin(__builtin_amdgcn_global_load_lds)
#define HAVE_GLL 1
#endif
#endif
#ifndef HAVE_GLL
#define HAVE_GLL 0
#endif

// ---------- helpers ----------
__device__ __forceinline__ u16 f2bf(float f) {
    u32 u = __float_as_uint(f);
    u32 r = u + 0x7fffu + ((u >> 16) & 1u);   // RNE
    return (u16)(r >> 16);
}
__device__ __forceinline__ float bf2f(u16 u) {
    return __uint_as_float(((u32)u) << 16);
}
__device__ __forceinline__ f32x4 mfma_bf16(s16x8 a, s16x8 b, f32x4 c) {
    return __builtin_amdgcn_mfma_f32_16x16x32_bf16(
        __builtin_bit_cast(bf16x8, a), __builtin_bit_cast(bf16x8, b), c, 0, 0, 0);
}
__device__ __forceinline__ f32x16 mfma32(s16x8 a, s16x8 b, f32x16 c) {
    return __builtin_amdgcn_mfma_f32_32x32x16_bf16(
        __builtin_bit_cast(bf16x8, a), __builtin_bit_cast(bf16x8, b), c, 0, 0, 0);
}
// v_cvt_pk_bf16_f32: D[15:0]=bf16(lo), D[31:16]=bf16(hi)  [T12 recipe, m214v22]
__device__ __forceinline__ u32 cvtpk(float lo, float hi) {
    u32 r;
    asm volatile("v_cvt_pk_bf16_f32 %0, %1, %2" : "=v"(r) : "v"(lo), "v"(hi));
    return r;
}
// async global->LDS: per-lane global src g; LDS dest = uniform base + lane*16B
__device__ __forceinline__ void gll16(const u16* __restrict__ g, u16* lds, int l) {
#if HAVE_GLL
    __builtin_amdgcn_global_load_lds((const __attribute__((address_space(1))) u32*)g,
                                     (__attribute__((address_space(3))) u32*)lds, 16, 0, 0);
#else
    *reinterpret_cast<uint4*>(lds + (l << 3)) = *reinterpret_cast<const uint4*>(g);
#endif
}

// ---------- fp32 -> bf16 elementwise ----------
__global__ __launch_bounds__(256) void k_cvt(const float* __restrict__ in,
                                             u16* __restrict__ out, int n4) {
    int i = blockIdx.x * 256 + threadIdx.x;
    int stride = gridDim.x * 256;
    for (; i < n4; i += stride) {
        float4 v = reinterpret_cast<const float4*>(in)[i];
        u32 lo = (u32)f2bf(v.x) | ((u32)f2bf(v.y) << 16);
        u32 hi = (u32)f2bf(v.z) | ((u32)f2bf(v.w) << 16);
        reinterpret_cast<uint2*>(out)[i] = make_uint2(lo, hi);
    }
}

// ---------- transpose + convert: in (R,C) fp32 -> out (C,R) bf16 ----------
__global__ __launch_bounds__(256) void k_tcvt(const float* __restrict__ in,
                                              u16* __restrict__ out, int R, int C) {
    __shared__ float lt[32][33];
    int r0 = blockIdx.x << 5, c0 = blockIdx.y << 5;
    int tid = threadIdx.x, rr = tid >> 5, cc = tid & 31;
#pragma unroll
    for (int j = 0; j < 4; ++j)
        lt[rr + j * 8][cc] = in[(size_t)(r0 + rr + j * 8) * C + c0 + cc];
    __syncthreads();
#pragma unroll
    for (int j = 0; j < 4; ++j)
        out[(size_t)(c0 + rr + j * 8) * R + r0 + cc] = f2bf(lt[cc][rr + j * 8]);
}

// ---------- bf16 GEMM (m97 structure): A (M,K), Bt (N,K), C (M,N) ----------
template <int OUT_BF16>
__global__ __launch_bounds__(256) void k_gemm(const u16* __restrict__ A,
                                              const u16* __restrict__ Bt,
                                              void* __restrict__ Cv,
                                              int M, int N, int K) {
    __shared__ u16 sA[128 * 64];
    __shared__ u16 sB[128 * 64];
    const int tid = threadIdx.x;
    const int w = tid >> 6, l = tid & 63;
    const int m0 = blockIdx.x << 7, n0 = blockIdx.y << 7;
    const int wr = (w >> 1) << 6, wc = (w & 1) << 6;
    const int lr = l & 15, lg = l >> 4;
    const int crow = l >> 3, ccol = (l & 7) << 3;
    f32x4 acc[4][4] = {};
    const int nkt = K >> 6;
    const u16* pA = A + (size_t)(m0 + (w << 5) + crow) * K + ccol;
    const u16* pB = Bt + (size_t)(n0 + (w << 5) + crow) * K + ccol;
    for (int kt = 0; kt < nkt; ++kt) {
        const int k0 = kt << 6;
        __syncthreads();
#pragma unroll
        for (int j = 0; j < 4; ++j) {
            gll16(pA + (size_t)(j << 3) * K + k0, &sA[((w << 2) + j) << 9], l);
            gll16(pB + (size_t)(j << 3) * K + k0, &sB[((w << 2) + j) << 9], l);
        }
        __syncthreads();
#pragma unroll
        for (int ks = 0; ks < 2; ++ks) {
            s16x8 af[4], bfr[4];
#pragma unroll
            for (int i = 0; i < 4; ++i) {
                af[i] = *reinterpret_cast<const s16x8*>(
                    &sA[((wr + (i << 4) + lr) << 6) + (ks << 5) + (lg << 3)]);
                bfr[i] = *reinterpret_cast<const s16x8*>(
                    &sB[((wc + (i << 4) + lr) << 6) + (ks << 5) + (lg << 3)]);
            }
#pragma unroll
            for (int i = 0; i < 4; ++i)
#pragma unroll
                for (int jn = 0; jn < 4; ++jn)
                    acc[i][jn] = mfma_bf16(af[i], bfr[jn], acc[i][jn]);
        }
    }
#pragma unroll
    for (int i = 0; i < 4; ++i) {
        int rbase = m0 + wr + (i << 4) + (lg << 2);
#pragma unroll
        for (int jn = 0; jn < 4; ++jn) {
            int c = n0 + wc + (jn << 4) + lr;
#pragma unroll
            for (int r = 0; r < 4; ++r) {
                size_t idx = (size_t)(rbase + r) * N + c;
                if (OUT_BF16)
                    ((u16*)Cv)[idx] = f2bf(acc[i][jn][r]);
                else
                    ((float*)Cv)[idx] = acc[i][jn][r];
            }
        }
    }
}

// ---------- RoPE + head-major relayout ----------
__global__ void k_rope(const u16* __restrict__ xin, int instride,
                       const int* __restrict__ pos, u16* __restrict__ xout,
                       int nH, float scale) {
    __shared__ float scs[64], sss[64];
    int bt = blockIdx.x;
    int b = bt >> 11, t = bt & 2047;
    int tid = threadIdx.x;
    if (tid < 64) {
        float p = (float)pos[bt];
        float fr = p * exp2f(-(float)tid * 0.20762050593045456f); // log2(1e4)/64
        float s, c;
        sincosf(fr, &s, &c);
        sss[tid] = s;
        scs[tid] = c;
    }
    __syncthreads();
    int e0 = tid << 3;
    int hh = e0 >> 7, d0 = e0 & 127;
    const u16* row = xin + (size_t)bt * instride + (hh << 7);
    u16 ov[8];
    if (d0 < 64) {
        const s16x8 x1 = *reinterpret_cast<const s16x8*>(row + d0);
        const s16x8 x2 = *reinterpret_cast<const s16x8*>(row + d0 + 64);
#pragma unroll
        for (int i = 0; i < 8; ++i) {
            int j = d0 + i;
            float v = bf2f((u16)x1[i]) * scs[j] - bf2f((u16)x2[i]) * sss[j];
            ov[i] = f2bf(v * scale);
        }
    } else {
        const s16x8 x1 = *reinterpret_cast<const s16x8*>(row + d0 - 64);
        const s16x8 x2 = *reinterpret_cast<const s16x8*>(row + d0);
#pragma unroll
        for (int i = 0; i < 8; ++i) {
            int j = d0 - 64 + i;
            float v = bf2f((u16)x1[i]) * sss[j] + bf2f((u16)x2[i]) * scs[j];
            ov[i] = f2bf(v * scale);
        }
    }
    u32 w0 = (u32)ov[0] | ((u32)ov[1] << 16);
    u32 w1 = (u32)ov[2] | ((u32)ov[3] << 16);
    u32 w2 = (u32)ov[4] | ((u32)ov[5] << 16);
    u32 w3 = (u32)ov[6] | ((u32)ov[7] << 16);
    u16* op = xout + ((size_t)(b * nH + hh) * 2048 + t) * 128 + d0;
    *reinterpret_cast<uint4*>(op) = make_uint4(w0, w1, w2, w3);
}

// ---------- V relayout: kvraw cols [512,1024) -> Vt (B*HKV, 128, T) ----------
__global__ __launch_bounds__(256) void k_vt(const u16* __restrict__ kvraw,
                                            u16* __restrict__ Vt) {
    __shared__ u16 lt[32][33];
    int t0 = blockIdx.x << 5, d0 = blockIdx.y << 5, bh = blockIdx.z;
    int b = bh >> 2, hk = bh & 3;
    int tid = threadIdx.x, rr = tid >> 5, cc = tid & 31;
#pragma unroll
    for (int j = 0; j < 4; ++j)
        lt[rr + j * 8][cc] =
            kvraw[(size_t)((b << 11) + t0 + rr + j * 8) * 1024 + 512 + (hk << 7) + d0 + cc];
    __syncthreads();
#pragma unroll
    for (int j = 0; j < 4; ++j)
        Vt[((size_t)(bh << 7) + d0 + rr + j * 8) * 2048 + t0 + cc] = lt[cc][rr + j * 8];
}

// ---------- causal GQA flash attention: swapped-QK^T 32x32, in-register softmax ----------
// Block = 4 waves; wave owns a 32-row q-strip. Two sequential passes per block:
// LOW band [128*px, +128), HIGH band [2048-128*(px+1), +128) -> 34 staged tiles
// per block uniformly. S^T = mfma32(K, Q): lane owns q=l&31; 16 regs = kv rows
// crow(r,hi) = (r&3)+8*(r>>2)+4*hi. Softmax fully in-register (1 shfl per reduce).
// P -> PV A-frag via v_cvt_pk_bf16_f32 + one shfl_xor(32) exchange. No P-LDS.
__global__ __launch_bounds__(256) void k_attn(const u16* __restrict__ Q,
                                              const u16* __restrict__ K,
                                              const u16* __restrict__ Vt,
                                              u16* __restrict__ ctx) {
    __shared__ u16 sK[2][64 * 128];   // [row kv 0..63][chunk c 0..15 @ slot c^(row&7)]
    __shared__ u16 sV[2][128 * 64];   // [row d 0..127][chunk c 0..7  @ slot c^(row&7)]
    const int tid = threadIdx.x;
    const int w = tid >> 6, l = tid & 63;
    const int ln = l & 31, hi = l >> 5;
    const int bx = blockIdx.x;
    // XCD-grouping: blocks of one (b,hk) share an XCD's L2 (K+V = 2MB fits 4MB)
    const int g = bx & 7, widx = bx >> 3;
    const int b = g >> 2, hk = g & 3;
    const int h = (hk << 2) + (widx & 3);
    const int px = widx >> 2;            // 0..7
    const u16* Qg = Q + (size_t)(b * 16 + h) * 2048 * 128;
    const u16* Kg = K + (size_t)(b * 4 + hk) * 2048 * 128;
    const u16* Vg = Vt + (size_t)(b * 4 + hk) * 128 * 2048;
    const int krow_c = l >> 4, kslot = l & 15;   // K stage: 4 rows x 16 slots
    const int vrow_c = l >> 3, vslot = l & 7;    // V stage: 8 rows x 8 slots

    auto STAGE = [&](int t, int buf) {
#pragma unroll
        for (int j = 0; j < 4; ++j) {
            int qc = (w << 2) + j;
            int krow = (qc << 2) + krow_c;                  // 0..63
            int kc = kslot ^ (krow & 7);                    // pre-swizzled src chunk
            gll16(Kg + (size_t)((t << 6) + krow) * 128 + (kc << 3), &sK[buf][qc << 9], l);
            int vrow = (qc << 3) + vrow_c;                  // 0..127 (d)
            int vc = vslot ^ (vrow & 7);
            gll16(Vg + (size_t)vrow * 2048 + (t << 6) + (vc << 3), &sV[buf][qc << 9], l);
        }
    };

#pragma unroll 1
    for (int pass = 0; pass < 2; ++pass) {
        const int band = (pass == 0) ? (px << 7) : (2048 - (px << 7) - 128);
        const int q0 = band + (w << 5);
        const int ntw = ((q0 + 31) >> 6) + 1;     // this wave's tile count
        const int ntmax = (band >> 6) + 2;        // block max (w=3)
        // Q fragments: B-op layout B[k=8*hi+i][q=ln]
        s16x8 aq[8];
#pragma unroll
        for (int ks = 0; ks < 8; ++ks)
            aq[ks] = *reinterpret_cast<const s16x8*>(
                Qg + (size_t)(q0 + ln) * 128 + (ks << 4) + (hi << 3));
        f32x16 O[4] = {};
        float m_s = -1e30f, l_s = 0.f;

        STAGE(0, 0);
        __syncthreads();
        int cur = 0;
        for (int t = 0; t < ntmax; ++t) {
            if (t + 1 < ntmax) STAGE(t + 1, cur ^ 1);
            if (t < ntw) {
#pragma unroll
                for (int ki = 0; ki < 2; ++ki) {
                    const int kvb = (t << 6) + (ki << 5);
                    if (kvb > q0 + 31) continue;   // fully-masked half-tile
                    // QK^T: S^T[kv][q], A=K from LDS, B=Q regs
                    f32x16 st = {};
#pragma unroll
                    for (int ks = 0; ks < 8; ++ks) {
                        int row = (ki << 5) + ln;
                        int slot = ((ks << 1) + hi) ^ (row & 7);
                        s16x8 af = *reinterpret_cast<const s16x8*>(
                            &sK[cur][(row << 7) + (slot << 3)]);
                        st = mfma32(af, aq[ks], st);
                    }
                    // causal mask on diagonal tile
                    if (t == ntw - 1) {
#pragma unroll
                        for (int r = 0; r < 16; ++r) {
                            int kv = kvb + (r & 3) + ((r >> 2) << 3) + (hi << 2);
                            if (kv > q0 + ln) st[r] = -3.0e38f;
                        }
                    }
                    // row max: in-lane tree + one cross-half exchange
                    float mx = fmaxf(st[0], st[1]);
#pragma unroll
                    for (int r = 2; r < 16; ++r) mx = fmaxf(mx, st[r]);
                    mx = fmaxf(mx, __shfl_xor(mx, 32));
                    // defer-max (THR=8 in log2 units)
                    if (__any(mx > m_s + 8.0f)) {
                        float mnew = fmaxf(m_s, mx);
                        float fac = exp2f(m_s - mnew);
                        m_s = mnew;
                        l_s *= fac;
#pragma unroll
                        for (int r = 0; r < 16; ++r) {
                            float fr = __shfl(fac, (r & 3) + ((r >> 2) << 3) + (hi << 2));
                            O[0][r] *= fr; O[1][r] *= fr; O[2][r] *= fr; O[3][r] *= fr;
                        }
                    }
                    // exp + row-sum (in-lane + one exchange)
                    float p[16];
                    float rs = 0.f;
#pragma unroll
                    for (int r = 0; r < 16; ++r) {
                        p[r] = exp2f(st[r] - m_s);
                        rs += p[r];
                    }
                    rs += __shfl_xor(rs, 32);
                    l_s += rs;
                    // pack P to bf16 + cross-half exchange -> PV A-frags
                    u32 wA0 = cvtpk(p[0], p[1]), wA1 = cvtpk(p[2], p[3]);
                    u32 wB0 = cvtpk(p[4], p[5]), wB1 = cvtpk(p[6], p[7]);
                    u32 wC0 = cvtpk(p[8], p[9]), wC1 = cvtpk(p[10], p[11]);
                    u32 wD0 = cvtpk(p[12], p[13]), wD1 = cvtpk(p[14], p[15]);
                    u32 x0 = __shfl_xor(hi ? wA0 : wB0, 32);
                    u32 x1 = __shfl_xor(hi ? wA1 : wB1, 32);
                    u32 x2 = __shfl_xor(hi ? wC0 : wD0, 32);
                    u32 x3 = __shfl_xor(hi ? wC1 : wD1, 32);
                    u32x4 pa0 = {hi ? x0 : wA0, hi ? x1 : wA1, hi ? wB0 : x0, hi ? wB1 : x1};
                    u32x4 pa1 = {hi ? x2 : wC0, hi ? x3 : wC1, hi ? wD0 : x2, hi ? wD1 : x3};
                    s16x8 ap0 = __builtin_bit_cast(s16x8, pa0);
                    s16x8 ap1 = __builtin_bit_cast(s16x8, pa1);
                    // PV: O[q][d] += P * V, B=V from LDS (d-major)
#pragma unroll
                    for (int ks2 = 0; ks2 < 2; ++ks2) {
                        s16x8 ap = ks2 ? ap1 : ap0;
#pragma unroll
                        for (int dblk = 0; dblk < 4; ++dblk) {
                            int row = (dblk << 5) + ln;
                            int slot = ((ki << 2) + (ks2 << 1) + hi) ^ (row & 7);
                            s16x8 bv = *reinterpret_cast<const s16x8*>(
                                &sV[cur][(row << 6) + (slot << 3)]);
                            O[dblk] = mfma32(ap, bv, O[dblk]);
                        }
                    }
                }
            }
            __syncthreads();   // drains prefetch vmcnt + all LDS reads
            cur ^= 1;
        }
        // epilogue: divide by l_s (broadcast per q-row), write ctx
        float inv = 1.f / l_s;
#pragma unroll
        for (int r = 0; r < 16; ++r) {
            int cr = (r & 3) + ((r >> 2) << 3) + (hi << 2);
            float ir = __shfl(inv, cr);
            int grow = (b << 11) + q0 + cr;
#pragma unroll
            for (int dblk = 0; dblk < 4; ++dblk)
                ctx[(size_t)grow * 2048 + (h << 7) + (dblk << 5) + ln] =
                    f2bf(O[dblk][r] * ir);
        }
        __syncthreads();   // LDS safe before next pass re-stages
    }
}

// ---------- launch ----------
extern "C" void kernel_launch(void* const* d_in, const int* in_sizes, int n_in,
                              void* d_out, int out_size, void* d_ws, size_t ws_size,
                              hipStream_t stream) {
    const float* Xq = (const float*)d_in[0];
    const float* Xkv = (const float*)d_in[1];
    const float* Wq = (const float*)d_in[2];
    const float* Wk = (const float*)d_in[3];
    const float* Wv = (const float*)d_in[4];
    const float* Wo = (const float*)d_in[5];
    const int* qpos = (const int*)d_in[6];
    const int* kpos = (const int*)d_in[7];
    float* out = (float*)d_out;
    char* ws = (char*)d_ws;
    size_t off = 0;
    auto alloc = [&](size_t elems) {
        u16* p = (u16*)(ws + off);
        off += elems * 2;
        return p;
    };
    u16* XqB = alloc(8388608);   // (4096,2048) bf16
    u16* XkvB = alloc(8388608);  // (4096,2048)
    u16* WqT = alloc(4194304);   // (2048,2048)  N x K
    u16* WkvT = alloc(2097152);  // (1024,2048)  [K | V]
    u16* WoT = alloc(4194304);   // (2048,2048)
    u16* qraw = alloc(8388608);  // (4096,2048)
    u16* kvraw = alloc(4194304); // (4096,1024)
    u16* Qb = alloc(8388608);    // (B,16,T,128)
    u16* Kb = alloc(2097152);    // (B,4,T,128)
    u16* Vtb = alloc(2097152);   // (B*4,128,T)
    u16* ctxb = alloc(8388608);  // (4096,2048)

    k_cvt<<<2048, 256, 0, stream>>>(Xq, XqB, 2097152);
    k_cvt<<<2048, 256, 0, stream>>>(Xkv, XkvB, 2097152);
    k_tcvt<<<dim3(64, 64), 256, 0, stream>>>(Wq, WqT, 2048, 2048);
    k_tcvt<<<dim3(64, 16), 256, 0, stream>>>(Wk, WkvT, 2048, 512);
    k_tcvt<<<dim3(64, 16), 256, 0, stream>>>(Wv, WkvT + (size_t)512 * 2048, 2048, 512);
    k_tcvt<<<dim3(64, 64), 256, 0, stream>>>(Wo, WoT, 2048, 2048);
    k_gemm<1><<<dim3(32, 16), 256, 0, stream>>>(XqB, WqT, qraw, 4096, 2048, 2048);
    k_gemm<1><<<dim3(32, 8), 256, 0, stream>>>(XkvB, WkvT, kvraw, 4096, 1024, 2048);
    // scale = 1/sqrt(128) * log2(e) folded into Q for base-2 softmax
    k_rope<<<4096, 256, 0, stream>>>(qraw, 2048, qpos, Qb, 16, 0.12751741641f);
    k_rope<<<4096, 64, 0, stream>>>(kvraw, 1024, kpos, Kb, 4, 1.0f);
    k_vt<<<dim3(64, 4, 8), 256, 0, stream>>>(kvraw, Vtb);
    k_attn<<<256, 256, 0, stream>>>(Qb, Kb, Vtb, ctxb);
    k_gemm<0><<<dim3(32, 16), 256, 0, stream>>>(ctxb, WoT, out, 4096, 2048, 2048);
}